// Round 12
// baseline (207.088 us; speedup 1.0000x reference)
//
#include <hip/hip_runtime.h>
#include <math.h>

#define BB 4
#define CC 64
#define TT 128
#define QQ 128
#define KK 8
#define HH 128
#define NN 512
#define LL 121
#define LPAD 135

typedef unsigned short ushort;
typedef __attribute__((ext_vector_type(8))) short short8;
typedef __attribute__((ext_vector_type(4))) float f32x4;
typedef __attribute__((ext_vector_type(4))) float float4v;

#define GLP(p) ((const __attribute__((address_space(1))) void*)(p))
#define LDP(p) ((__attribute__((address_space(3))) void*)(p))

__device__ __forceinline__ ushort f2bf(float x) {
  unsigned u = __float_as_uint(x);
  unsigned r = (u + 0x7FFFu + ((u >> 16) & 1u)) >> 16;
  return (ushort)r;
}

// ---- merged prep: LayerNorm->xT, weight transforms, zero page ----
__global__ __launch_bounds__(256)
void prep_all(const float* __restrict__ f, const float* __restrict__ gamma,
              const float* __restrict__ beta, const float* __restrict__ wf,
              const float* __restrict__ wb, const float* __restrict__ ctw,
              ushort* __restrict__ xT, ushort* __restrict__ Wt,
              ushort* __restrict__ Bct, ushort* __restrict__ zpage) {
  int bid = blockIdx.x, tid = threadIdx.x;
  if (bid < 256) {                       // --- LayerNorm -> xT[n][q][c] bf16
    int p = bid * 256 + tid;
    int q = p & (QQ - 1);
    int t = (p >> 7) & (TT - 1);
    int b = p >> 14;
    const float* base = f + (size_t)b * CC * TT * QQ + (size_t)t * QQ + q;
    float v[64];
#pragma unroll
    for (int c = 0; c < 64; ++c) v[c] = base[(size_t)c * TT * QQ];
    float s = 0.f, s2 = 0.f;
#pragma unroll
    for (int c = 0; c < 64; ++c) { s += v[c]; s2 += v[c] * v[c]; }
    float mu = s * (1.f / CC);
    float var = s2 * (1.f / CC) - mu * mu;
    float rs = rsqrtf(var + 1e-5f);
    int n = b * TT + t;
    ushort* dst = xT + (size_t)n * (CC * QQ) + (size_t)q * CC;
#pragma unroll
    for (int v8 = 0; v8 < 8; ++v8) {
      short8 ov;
#pragma unroll
      for (int e = 0; e < 8; ++e) {
        int c = v8 * 8 + e;
        ov[e] = (short)f2bf((v[c] - mu) * rs * gamma[c] + beta[c]);
      }
      *(short8*)(dst + v8 * 8) = ov;
    }
  } else if (bid < 2816) {               // --- Wt / Bct transforms
    int idx = (bid - 256) * 256 + tid;
    if (idx < 524288) {
      // Wt[r][d], d=k*64+c; col r: dir=r>>9,t=r&511,
      // h=(t>>7)*32+((t>>6)&1)*16+(t&15), quad=(t>>4)&3
      int r = idx >> 9, d = idx & 511;
      int k = d >> 6, c = d & 63;
      int dir = r >> 9, t = r & 511;
      int h = (t >> 7) * 32 + ((t >> 6) & 1) * 16 + (t & 15);
      int quad = (t >> 4) & 3;
      const float* w = dir ? wb : wf;
      Wt[idx] = f2bf(w[(size_t)(c * 8 + k) * 512 + quad * 128 + h]);
    } else {
      int i2 = idx - 524288;             // 64*2048
      int c = i2 >> 11, d = i2 & 2047;
      int k = d >> 8, j = d & 255;
      Bct[i2] = f2bf(ctw[(size_t)j * (CC * KK) + c * KK + k]);
    }
  } else {                               // --- zero page (512 B)
    if (tid < 128) ((unsigned*)zpage)[tid] = 0u;
  }
}

// ---- fused MFMA GEMM, BM=256 (2 n) x BN=256, 512 threads, 8 waves ----
// Wave w: nsub = w>>2 (which n), jb = w&3 (64-col block). Each wave owns the
// FULL 128-l chain of its n for 16 h, all 4 quads -> wave-local scan epilogue.
// A-tile LDS row rIdx (low 7 bits permuted): thread rows are CONTIGUOUS
// l = lk*32 + m*4 + g. Single-buffer K-loop, XOR-swizzled staging.
__global__ __launch_bounds__(512, 3)
void gemm_mfma(const ushort* __restrict__ xT, const ushort* __restrict__ Wt,
               const float* __restrict__ b_fwd, const float* __restrict__ b_bwd,
               ushort* __restrict__ hp, int n0) {
  __shared__ __align__(16) char smem[65536];
  ushort* As = (ushort*)smem;                 // 32 KB (256x64): rows 0..127 n0, 128..255 n1
  ushort* Bs = (ushort*)(smem + 32768);       // 32 KB (256x64)

  int tid = threadIdx.x;
  int nl = blockIdx.y;                        // n-pair index
  int r0 = blockIdx.x * 256;
  int lane = tid & 63, w = tid >> 6;
  int nsub = w >> 2, jb = w & 3;
  int lrow = lane & 15, lk = lane >> 4;
  f32x4 acc[8][4] = {};
  const ushort* xTb = xT + (size_t)(n0 + nl * 2) * (CC * QQ);
  for (int ks = 0; ks < 8; ++ks) {
    if (ks) __syncthreads();
#pragma unroll
    for (int i = 0; i < 4; ++i) {            // A: gather-unfold, permuted rows
      int p = i * 512 + tid;
      int row = p >> 3, s = (p & 7) ^ (row & 7);
      int low = row & 127;
      int grow = ((low & 0x0C) << 3) | ((low & 0x70) >> 2) | (low & 3);
      const ushort* g = xTb + (size_t)(row >> 7) * (CC * QQ)
                      + (size_t)(grow + ks) * CC + s * 8;
      ushort* l = &As[(size_t)(i * 512 + (tid & 448)) * 8];
      __builtin_amdgcn_global_load_lds(GLP(g), LDP(l), 16, 0, 0);
    }
#pragma unroll
    for (int i = 0; i < 4; ++i) {            // B: 256 rows
      int p = i * 512 + tid;
      int row = p >> 3, s = (p & 7) ^ (row & 7);
      const ushort* g = Wt + (size_t)(r0 + row) * 512 + ks * 64 + s * 8;
      ushort* l = &Bs[(size_t)(i * 512 + (tid & 448)) * 8];
      __builtin_amdgcn_global_load_lds(GLP(g), LDP(l), 16, 0, 0);
    }
    __syncthreads();
#pragma unroll
    for (int s = 0; s < 2; ++s) {
      short8 a[8], b[4];
#pragma unroll
      for (int m = 0; m < 8; ++m) {
        int r = nsub * 128 + m * 16 + lrow;
        int slot = (s * 4 + lk) ^ (r & 7);
        a[m] = *(const short8*)&As[r * 64 + slot * 8];
      }
#pragma unroll
      for (int nn = 0; nn < 4; ++nn) {
        int j = jb * 64 + nn * 16 + lrow;
        int slot = (s * 4 + lk) ^ (j & 7);
        b[nn] = *(const short8*)&Bs[j * 64 + slot * 8];
      }
#pragma unroll
      for (int m = 0; m < 8; ++m)
#pragma unroll
        for (int nn = 0; nn < 4; ++nn)
          acc[m][nn] = __builtin_amdgcn_mfma_f32_16x16x32_bf16(
              a[m], b[nn], acc[m][nn], 0, 0, 0);
    }
  }
  // ---- epilogue: wave-local scan, no barriers ----
  int dirf = r0 >> 9;
  int hgroup = ((r0 & 511) >> 7) + (jb >> 1);
  int h = hgroup * 32 + (jb & 1) * 16 + lrow;
  const float* bias = dirf ? b_bwd : b_fwd;
  float bf = bias[h], br = bias[128 + h];

  // serial scan of this thread's 32 contiguous l, in-place into acc[m][0/1]
  float F = 1.f, U = 0.f;
  if (dirf == 0) {
#pragma unroll
    for (int m = 0; m < 8; ++m)
#pragma unroll
      for (int g = 0; g < 4; ++g) {
        int l = lk * 32 + m * 4 + g;
        float xt = acc[m][0][g], fp = acc[m][1][g];
        float fg = 1.f / (1.f + __expf(-(fp + bf)));
        float u = (1.f - fg) * xt;
        if (l > 120) { fg = 1.f; u = 0.f; }   // identity (kills garbage rows)
        U = fg * U + u;
        F = fg * F;
        acc[m][0][g] = F; acc[m][1][g] = U;
      }
  } else {
#pragma unroll
    for (int m = 7; m >= 0; --m)
#pragma unroll
      for (int g = 3; g >= 0; --g) {
        int l = lk * 32 + m * 4 + g;
        float xt = acc[m][0][g], fp = acc[m][1][g];
        float fg = 1.f / (1.f + __expf(-(fp + bf)));
        float u = (1.f - fg) * xt;
        if (l > 120) { fg = 1.f; u = 0.f; }
        U = fg * U + u;
        F = fg * F;
        acc[m][0][g] = F; acc[m][1][g] = U;
      }
  }
  // compose across lk chunks (full 128-l chain in this wave): 8 shuffles
  int e = dirf ? 3 - lk : lk;
  float lpU = 0.f;
#pragma unroll
  for (int j = 0; j < 4; ++j) {
    int jl = dirf ? 3 - j : j;
    float tF = __shfl(F, (jl << 4) + lrow);
    float tU = __shfl(U, (jl << 4) + lrow);
    if (j < e) lpU = tF * lpU + tU;
  }
  float cinit = lpU;
  // apply: c = U + F*cinit; h_out = r*tanh(c) + (1-r)*xp -> bf16 hp
  // UNCONDITIONAL stores: garbage l>120 land in hp rows 128..134 (never read;
  // conv redirects pad reads to the zero page).
  ushort* hpn = hp + (size_t)(nl * 2 + nsub) * LPAD * 256;
  int colbase = dirf * 128 + hgroup * 32 + (jb & 1) * 16;
#pragma unroll
  for (int m = 0; m < 8; ++m) {
#pragma unroll
    for (int g = 0; g < 4; ++g) {
      int l = lk * 32 + m * 4 + g;
      float c = acc[m][1][g] + acc[m][0][g] * cinit;
      float rp = acc[m][2][g];
      float rg = 1.f / (1.f + __expf(-(rp + br)));
      float e2 = __expf(2.f * c);
      float th = (e2 - 1.f) / (e2 + 1.f);
      float ho = rg * th + (1.f - rg) * acc[m][3][g];
      hpn[(size_t)(l + 7) * 256 + colbase + lrow] = f2bf(ho);
    }
  }
}

// ---------------- ConvTranspose as MFMA GEMM, persistent-Hs version ----------------
// hp[n] is staged ONCE per j-half into LDS (Hs); all 8 taps read it with a row
// offset. Only the small B-tile (64x64) is re-staged per K-step (double-buffered).
__global__ __launch_bounds__(256)
void conv_mfma(const ushort* __restrict__ hp, const ushort* __restrict__ Bct,
               const ushort* __restrict__ zpage, const float* __restrict__ ctb,
               const float* __restrict__ feat, float* __restrict__ out, int n0) {
  __shared__ __align__(16) ushort Hs[144 * 128];   // 36,864 B (rows 135..143 = slop)
  __shared__ __align__(16) ushort Bs[2][64 * 64];  // 16,384 B
  int tid = threadIdx.x;
  int nl = blockIdx.x;
  int lane = tid & 63, w = tid >> 6;
  int wr0 = (w >> 1) * 64, wc0 = (w & 1) * 32;
  int lrow = lane & 15, lk = lane >> 4;
  f32x4 acc[4][2] = {};
  const ushort* hpn = hp + (size_t)nl * LPAD * 256;

#define CONV_BSTAGE(T, BSEL)                                               \
  {                                                                        \
    int kk_ = (T) >> 1, sub_ = (T) & 1;                                    \
    _Pragma("unroll")                                                      \
    for (int i = 0; i < 2; ++i) {                                          \
      int p = i * 256 + tid;                                               \
      int row = p >> 3, ds = p & 7;                                        \
      const ushort* g = Bct + (size_t)row * 2048 + kk_ * 256 + jh * 128    \
                      + sub_ * 64 + (ds ^ (row & 7)) * 8;                  \
      ushort* l = &Bs[BSEL][(size_t)(i * 256 + (tid & 192)) * 8];          \
      __builtin_amdgcn_global_load_lds(GLP(g), LDP(l), 16, 0, 0);          \
    }                                                                      \
  }

  for (int jh = 0; jh < 2; ++jh) {
    // stage Hs: hp rows 0..143 of this j-half; rows outside [7,127] -> zeros
#pragma unroll
    for (int r = 0; r < 9; ++r) {
      int p = r * 256 + tid;
      int row = p >> 4, ds = p & 15;
      int cs = (ds & 8) | ((ds & 7) ^ (row & 7));
      const ushort* g = ((unsigned)(row - 7) <= 120u)
          ? hpn + (size_t)row * 256 + jh * 128 + cs * 8
          : zpage;
      ushort* l = &Hs[(size_t)(r * 256 + (tid & 192)) * 8];
      __builtin_amdgcn_global_load_lds(GLP(g), LDP(l), 16, 0, 0);
    }
    CONV_BSTAGE(0, 0);
    __syncthreads();
    for (int t = 0; t < 16; ++t) {
      int cur = t & 1;
      if (t < 15) CONV_BSTAGE(t + 1, cur ^ 1);
      int kk = t >> 1, sub = t & 1;
#pragma unroll
      for (int s = 0; s < 2; ++s) {
        short8 a[4], b[2];
#pragma unroll
        for (int m = 0; m < 4; ++m) {
          int row = wr0 + m * 16 + lrow + 7 - kk;
          int slot = (sub * 8) | ((s * 4 + lk) ^ (row & 7));
          a[m] = *(const short8*)&Hs[row * 128 + slot * 8];
        }
#pragma unroll
        for (int nn = 0; nn < 2; ++nn) {
          int c = wc0 + nn * 16 + lrow;
          int slot = (s * 4 + lk) ^ (c & 7);
          b[nn] = *(const short8*)&Bs[cur][c * 64 + slot * 8];
        }
#pragma unroll
        for (int m = 0; m < 4; ++m)
#pragma unroll
          for (int nn = 0; nn < 2; ++nn)
            acc[m][nn] = __builtin_amdgcn_mfma_f32_16x16x32_bf16(
                a[m], b[nn], acc[m][nn], 0, 0, 0);
      }
      __syncthreads();
    }
  }
#undef CONV_BSTAGE
  int n = n0 + nl;
  int b = n >> 7, t = n & 127;
#pragma unroll
  for (int m = 0; m < 4; ++m) {
    int q0 = wr0 + m * 16 + lk * 4;
#pragma unroll
    for (int nn = 0; nn < 2; ++nn) {
      int c = wc0 + nn * 16 + lrow;
      size_t idx = (size_t)b * (CC * TT * QQ) + (size_t)c * (TT * QQ)
                 + (size_t)t * QQ + q0;
      float4v fv = *(const float4v*)&feat[idx];
      float cb = ctb[c];
      float4v ov;
#pragma unroll
      for (int g = 0; g < 4; ++g) ov[g] = acc[m][nn][g] + cb + fv[g];
      *(float4v*)&out[idx] = ov;
    }
  }
}

extern "C" void kernel_launch(void* const* d_in, const int* in_sizes, int n_in,
                              void* d_out, int out_size, void* d_ws, size_t ws_size,
                              hipStream_t stream) {
  const float* feat  = (const float*)d_in[0];
  const float* gamma = (const float*)d_in[1];
  const float* beta  = (const float*)d_in[2];
  const float* w_fwd = (const float*)d_in[3];
  const float* b_fwd = (const float*)d_in[4];
  const float* w_bwd = (const float*)d_in[5];
  const float* b_bwd = (const float*)d_in[6];
  const float* ct_w  = (const float*)d_in[7];
  const float* ct_b  = (const float*)d_in[8];
  float* out = (float*)d_out;

  char* wsb = (char*)d_ws;
  ushort* xT  = (ushort*)wsb;                         // 8,388,608 B
  ushort* Wt  = (ushort*)(wsb + 8388608);             // 1,048,576 B
  ushort* Bct = (ushort*)(wsb + 9437184);             //   262,144 B
  ushort* zpg = (ushort*)(wsb + 9699328);             //       512 B
  size_t persist = 9699840;
  size_t per_n = 69120u;                              // hp only
  int NC = 4;
  for (int cand = 512; cand >= 4; cand >>= 1) {
    if (persist + (size_t)cand * per_n <= ws_size) { NC = cand; break; }
  }
  ushort* hpc = (ushort*)(wsb + persist);

  prep_all<<<dim3(2817), dim3(256), 0, stream>>>(feat, gamma, beta, w_fwd,
                                                 w_bwd, ct_w, xT, Wt, Bct, zpg);

  for (int n0 = 0; n0 < NN; n0 += NC) {
    gemm_mfma<<<dim3(4, NC / 2), dim3(512), 0, stream>>>(xT, Wt, b_fwd, b_bwd,
                                                         hpc, n0);
    conv_mfma<<<dim3(NC), dim3(256), 0, stream>>>(hpc, Bct, zpg, ct_b, feat,
                                                  out, n0);
  }
}

// Round 13
// 133.802 us; speedup vs baseline: 1.5477x; 1.5477x over previous
//
#include <hip/hip_runtime.h>
#include <math.h>

#define BB 4
#define CC 64
#define TT 128
#define QQ 128
#define KK 8
#define HH 128
#define NN 512
#define LL 121
#define LPAD 135

typedef unsigned short ushort;
typedef __attribute__((ext_vector_type(8))) short short8;
typedef __attribute__((ext_vector_type(4))) float f32x4;
typedef __attribute__((ext_vector_type(4))) float float4v;

#define GLP(p) ((const __attribute__((address_space(1))) void*)(p))
#define LDP(p) ((__attribute__((address_space(3))) void*)(p))

__device__ __forceinline__ ushort f2bf(float x) {
  unsigned u = __float_as_uint(x);
  unsigned r = (u + 0x7FFFu + ((u >> 16) & 1u)) >> 16;
  return (ushort)r;
}

// ---- merged prep: LayerNorm->xT, weight transforms, zero page ----
__global__ __launch_bounds__(256)
void prep_all(const float* __restrict__ f, const float* __restrict__ gamma,
              const float* __restrict__ beta, const float* __restrict__ wf,
              const float* __restrict__ wb, const float* __restrict__ ctw,
              ushort* __restrict__ xT, ushort* __restrict__ Wt,
              ushort* __restrict__ Bct, ushort* __restrict__ zpage) {
  int bid = blockIdx.x, tid = threadIdx.x;
  if (bid < 256) {                       // --- LayerNorm -> xT[n][q][c] bf16
    int p = bid * 256 + tid;
    int q = p & (QQ - 1);
    int t = (p >> 7) & (TT - 1);
    int b = p >> 14;
    const float* base = f + (size_t)b * CC * TT * QQ + (size_t)t * QQ + q;
    float v[64];
#pragma unroll
    for (int c = 0; c < 64; ++c) v[c] = base[(size_t)c * TT * QQ];
    float s = 0.f, s2 = 0.f;
#pragma unroll
    for (int c = 0; c < 64; ++c) { s += v[c]; s2 += v[c] * v[c]; }
    float mu = s * (1.f / CC);
    float var = s2 * (1.f / CC) - mu * mu;
    float rs = rsqrtf(var + 1e-5f);
    int n = b * TT + t;
    ushort* dst = xT + (size_t)n * (CC * QQ) + (size_t)q * CC;
#pragma unroll
    for (int v8 = 0; v8 < 8; ++v8) {
      short8 ov;
#pragma unroll
      for (int e = 0; e < 8; ++e) {
        int c = v8 * 8 + e;
        ov[e] = (short)f2bf((v[c] - mu) * rs * gamma[c] + beta[c]);
      }
      *(short8*)(dst + v8 * 8) = ov;
    }
  } else if (bid < 2816) {               // --- Wt / Bct transforms
    int idx = (bid - 256) * 256 + tid;
    if (idx < 524288) {
      // Wt[r][d], d=k*64+c; col r: dir=r>>9,t=r&511,
      // h=(t>>7)*32+((t>>6)&1)*16+(t&15), quad=(t>>4)&3
      int r = idx >> 9, d = idx & 511;
      int k = d >> 6, c = d & 63;
      int dir = r >> 9, t = r & 511;
      int h = (t >> 7) * 32 + ((t >> 6) & 1) * 16 + (t & 15);
      int quad = (t >> 4) & 3;
      const float* w = dir ? wb : wf;
      Wt[idx] = f2bf(w[(size_t)(c * 8 + k) * 512 + quad * 128 + h]);
    } else {
      int i2 = idx - 524288;             // 64*2048
      int c = i2 >> 11, d = i2 & 2047;
      int k = d >> 8, j = d & 255;
      Bct[i2] = f2bf(ctw[(size_t)j * (CC * KK) + c * KK + k]);
    }
  } else {                               // --- zero page (512 B)
    if (tid < 128) ((unsigned*)zpage)[tid] = 0u;
  }
}

// ---- fused MFMA GEMM, BM=256 (2 n) x BN=256, 512 threads, 8 waves ----
// Wave w: nsub = w>>2 (which n), jb = w&3 (64-col block). Each wave owns the
// FULL 128-l chain of its n for 16 h, all 4 quads -> wave-local scan epilogue.
// __launch_bounds__(512,2): VGPR cap 256 (R12's (512,3) capped at ~170 and
// SPILLED the accumulator -> 2x regression; counters: VGPR 84, WRITE 276 MB).
__global__ __launch_bounds__(512, 2)
void gemm_mfma(const ushort* __restrict__ xT, const ushort* __restrict__ Wt,
               const float* __restrict__ b_fwd, const float* __restrict__ b_bwd,
               ushort* __restrict__ hp, int n0) {
  __shared__ __align__(16) char smem[65536];
  ushort* As = (ushort*)smem;                 // 32 KB (256x64): rows 0..127 n0, 128..255 n1
  ushort* Bs = (ushort*)(smem + 32768);       // 32 KB (256x64)

  int tid = threadIdx.x;
  int nl = blockIdx.y;                        // n-pair index
  int r0 = blockIdx.x * 256;
  int lane = tid & 63, w = tid >> 6;
  int nsub = w >> 2, jb = w & 3;
  int lrow = lane & 15, lk = lane >> 4;
  f32x4 acc[8][4] = {};
  const ushort* xTb = xT + (size_t)(n0 + nl * 2) * (CC * QQ);
  for (int ks = 0; ks < 8; ++ks) {
    if (ks) __syncthreads();
#pragma unroll
    for (int i = 0; i < 4; ++i) {            // A: gather-unfold, permuted rows
      int p = i * 512 + tid;
      int row = p >> 3, s = (p & 7) ^ (row & 7);
      int low = row & 127;
      int grow = ((low & 0x0C) << 3) | ((low & 0x70) >> 2) | (low & 3);
      const ushort* g = xTb + (size_t)(row >> 7) * (CC * QQ)
                      + (size_t)(grow + ks) * CC + s * 8;
      ushort* l = &As[(size_t)(i * 512 + (tid & 448)) * 8];
      __builtin_amdgcn_global_load_lds(GLP(g), LDP(l), 16, 0, 0);
    }
#pragma unroll
    for (int i = 0; i < 4; ++i) {            // B: 256 rows
      int p = i * 512 + tid;
      int row = p >> 3, s = (p & 7) ^ (row & 7);
      const ushort* g = Wt + (size_t)(r0 + row) * 512 + ks * 64 + s * 8;
      ushort* l = &Bs[(size_t)(i * 512 + (tid & 448)) * 8];
      __builtin_amdgcn_global_load_lds(GLP(g), LDP(l), 16, 0, 0);
    }
    __syncthreads();
#pragma unroll
    for (int s = 0; s < 2; ++s) {
      short8 a[8], b[4];
#pragma unroll
      for (int m = 0; m < 8; ++m) {
        int r = nsub * 128 + m * 16 + lrow;
        int slot = (s * 4 + lk) ^ (r & 7);
        a[m] = *(const short8*)&As[r * 64 + slot * 8];
      }
#pragma unroll
      for (int nn = 0; nn < 4; ++nn) {
        int j = jb * 64 + nn * 16 + lrow;
        int slot = (s * 4 + lk) ^ (j & 7);
        b[nn] = *(const short8*)&Bs[j * 64 + slot * 8];
      }
#pragma unroll
      for (int m = 0; m < 8; ++m)
#pragma unroll
        for (int nn = 0; nn < 4; ++nn)
          acc[m][nn] = __builtin_amdgcn_mfma_f32_16x16x32_bf16(
              a[m], b[nn], acc[m][nn], 0, 0, 0);
    }
  }
  // ---- epilogue: wave-local scan, no barriers ----
  int dirf = r0 >> 9;
  int hgroup = ((r0 & 511) >> 7) + (jb >> 1);
  int h = hgroup * 32 + (jb & 1) * 16 + lrow;
  const float* bias = dirf ? b_bwd : b_fwd;
  float bf = bias[h], br = bias[128 + h];

  // serial scan of this thread's 32 contiguous l, in-place into acc[m][0/1]
  float F = 1.f, U = 0.f;
  if (dirf == 0) {
#pragma unroll
    for (int m = 0; m < 8; ++m)
#pragma unroll
      for (int g = 0; g < 4; ++g) {
        int l = lk * 32 + m * 4 + g;
        float xt = acc[m][0][g], fp = acc[m][1][g];
        float fg = 1.f / (1.f + __expf(-(fp + bf)));
        float u = (1.f - fg) * xt;
        if (l > 120) { fg = 1.f; u = 0.f; }   // identity (kills garbage rows)
        U = fg * U + u;
        F = fg * F;
        acc[m][0][g] = F; acc[m][1][g] = U;
      }
  } else {
#pragma unroll
    for (int m = 7; m >= 0; --m)
#pragma unroll
      for (int g = 3; g >= 0; --g) {
        int l = lk * 32 + m * 4 + g;
        float xt = acc[m][0][g], fp = acc[m][1][g];
        float fg = 1.f / (1.f + __expf(-(fp + bf)));
        float u = (1.f - fg) * xt;
        if (l > 120) { fg = 1.f; u = 0.f; }
        U = fg * U + u;
        F = fg * F;
        acc[m][0][g] = F; acc[m][1][g] = U;
      }
  }
  // compose across lk chunks (full 128-l chain in this wave): 8 shuffles
  int e = dirf ? 3 - lk : lk;
  float lpU = 0.f;
#pragma unroll
  for (int j = 0; j < 4; ++j) {
    int jl = dirf ? 3 - j : j;
    float tF = __shfl(F, (jl << 4) + lrow);
    float tU = __shfl(U, (jl << 4) + lrow);
    if (j < e) lpU = tF * lpU + tU;
  }
  float cinit = lpU;
  // apply: c = U + F*cinit; h_out = r*tanh(c) + (1-r)*xp -> bf16 hp
  // UNCONDITIONAL stores: garbage l>120 land in hp rows 128..134 (never read;
  // conv redirects pad reads to the zero page).
  ushort* hpn = hp + (size_t)(nl * 2 + nsub) * LPAD * 256;
  int colbase = dirf * 128 + hgroup * 32 + (jb & 1) * 16;
#pragma unroll
  for (int m = 0; m < 8; ++m) {
#pragma unroll
    for (int g = 0; g < 4; ++g) {
      int l = lk * 32 + m * 4 + g;
      float c = acc[m][1][g] + acc[m][0][g] * cinit;
      float rp = acc[m][2][g];
      float rg = 1.f / (1.f + __expf(-(rp + br)));
      float e2 = __expf(2.f * c);
      float th = (e2 - 1.f) / (e2 + 1.f);
      float ho = rg * th + (1.f - rg) * acc[m][3][g];
      hpn[(size_t)(l + 7) * 256 + colbase + lrow] = f2bf(ho);
    }
  }
}

// ---------------- ConvTranspose as MFMA GEMM, persistent-Hs version ----------------
// hp[n] is staged ONCE per j-half into LDS (Hs); all 8 taps read it with a row
// offset. Only the small B-tile (64x64) is re-staged per K-step (double-buffered).
__global__ __launch_bounds__(256)
void conv_mfma(const ushort* __restrict__ hp, const ushort* __restrict__ Bct,
               const ushort* __restrict__ zpage, const float* __restrict__ ctb,
               const float* __restrict__ feat, float* __restrict__ out, int n0) {
  __shared__ __align__(16) ushort Hs[144 * 128];   // 36,864 B (rows 135..143 = slop)
  __shared__ __align__(16) ushort Bs[2][64 * 64];  // 16,384 B
  int tid = threadIdx.x;
  int nl = blockIdx.x;
  int lane = tid & 63, w = tid >> 6;
  int wr0 = (w >> 1) * 64, wc0 = (w & 1) * 32;
  int lrow = lane & 15, lk = lane >> 4;
  f32x4 acc[4][2] = {};
  const ushort* hpn = hp + (size_t)nl * LPAD * 256;

#define CONV_BSTAGE(T, BSEL)                                               \
  {                                                                        \
    int kk_ = (T) >> 1, sub_ = (T) & 1;                                    \
    _Pragma("unroll")                                                      \
    for (int i = 0; i < 2; ++i) {                                          \
      int p = i * 256 + tid;                                               \
      int row = p >> 3, ds = p & 7;                                        \
      const ushort* g = Bct + (size_t)row * 2048 + kk_ * 256 + jh * 128    \
                      + sub_ * 64 + (ds ^ (row & 7)) * 8;                  \
      ushort* l = &Bs[BSEL][(size_t)(i * 256 + (tid & 192)) * 8];          \
      __builtin_amdgcn_global_load_lds(GLP(g), LDP(l), 16, 0, 0);          \
    }                                                                      \
  }

  for (int jh = 0; jh < 2; ++jh) {
    // stage Hs: hp rows 0..143 of this j-half; rows outside [7,127] -> zeros
#pragma unroll
    for (int r = 0; r < 9; ++r) {
      int p = r * 256 + tid;
      int row = p >> 4, ds = p & 15;
      int cs = (ds & 8) | ((ds & 7) ^ (row & 7));
      const ushort* g = ((unsigned)(row - 7) <= 120u)
          ? hpn + (size_t)row * 256 + jh * 128 + cs * 8
          : zpage;
      ushort* l = &Hs[(size_t)(r * 256 + (tid & 192)) * 8];
      __builtin_amdgcn_global_load_lds(GLP(g), LDP(l), 16, 0, 0);
    }
    CONV_BSTAGE(0, 0);
    __syncthreads();
    for (int t = 0; t < 16; ++t) {
      int cur = t & 1;
      if (t < 15) CONV_BSTAGE(t + 1, cur ^ 1);
      int kk = t >> 1, sub = t & 1;
#pragma unroll
      for (int s = 0; s < 2; ++s) {
        short8 a[4], b[2];
#pragma unroll
        for (int m = 0; m < 4; ++m) {
          int row = wr0 + m * 16 + lrow + 7 - kk;
          int slot = (sub * 8) | ((s * 4 + lk) ^ (row & 7));
          a[m] = *(const short8*)&Hs[row * 128 + slot * 8];
        }
#pragma unroll
        for (int nn = 0; nn < 2; ++nn) {
          int c = wc0 + nn * 16 + lrow;
          int slot = (s * 4 + lk) ^ (c & 7);
          b[nn] = *(const short8*)&Bs[cur][c * 64 + slot * 8];
        }
#pragma unroll
        for (int m = 0; m < 4; ++m)
#pragma unroll
          for (int nn = 0; nn < 2; ++nn)
            acc[m][nn] = __builtin_amdgcn_mfma_f32_16x16x32_bf16(
                a[m], b[nn], acc[m][nn], 0, 0, 0);
      }
      __syncthreads();
    }
  }
#undef CONV_BSTAGE
  int n = n0 + nl;
  int b = n >> 7, t = n & 127;
#pragma unroll
  for (int m = 0; m < 4; ++m) {
    int q0 = wr0 + m * 16 + lk * 4;
#pragma unroll
    for (int nn = 0; nn < 2; ++nn) {
      int c = wc0 + nn * 16 + lrow;
      size_t idx = (size_t)b * (CC * TT * QQ) + (size_t)c * (TT * QQ)
                 + (size_t)t * QQ + q0;
      float4v fv = *(const float4v*)&feat[idx];
      float cb = ctb[c];
      float4v ov;
#pragma unroll
      for (int g = 0; g < 4; ++g) ov[g] = acc[m][nn][g] + cb + fv[g];
      *(float4v*)&out[idx] = ov;
    }
  }
}

extern "C" void kernel_launch(void* const* d_in, const int* in_sizes, int n_in,
                              void* d_out, int out_size, void* d_ws, size_t ws_size,
                              hipStream_t stream) {
  const float* feat  = (const float*)d_in[0];
  const float* gamma = (const float*)d_in[1];
  const float* beta  = (const float*)d_in[2];
  const float* w_fwd = (const float*)d_in[3];
  const float* b_fwd = (const float*)d_in[4];
  const float* w_bwd = (const float*)d_in[5];
  const float* b_bwd = (const float*)d_in[6];
  const float* ct_w  = (const float*)d_in[7];
  const float* ct_b  = (const float*)d_in[8];
  float* out = (float*)d_out;

  char* wsb = (char*)d_ws;
  ushort* xT  = (ushort*)wsb;                         // 8,388,608 B
  ushort* Wt  = (ushort*)(wsb + 8388608);             // 1,048,576 B
  ushort* Bct = (ushort*)(wsb + 9437184);             //   262,144 B
  ushort* zpg = (ushort*)(wsb + 9699328);             //       512 B
  size_t persist = 9699840;
  size_t per_n = 69120u;                              // hp only
  int NC = 4;
  for (int cand = 512; cand >= 4; cand >>= 1) {
    if (persist + (size_t)cand * per_n <= ws_size) { NC = cand; break; }
  }
  ushort* hpc = (ushort*)(wsb + persist);

  prep_all<<<dim3(2817), dim3(256), 0, stream>>>(feat, gamma, beta, w_fwd,
                                                 w_bwd, ct_w, xT, Wt, Bct, zpg);

  for (int n0 = 0; n0 < NN; n0 += NC) {
    gemm_mfma<<<dim3(4, NC / 2), dim3(512), 0, stream>>>(xT, Wt, b_fwd, b_bwd,
                                                         hpc, n0);
    conv_mfma<<<dim3(NC), dim3(256), 0, stream>>>(hpc, Bct, zpg, ct_b, feat,
                                                  out, n0);
  }
}

// Round 14
// 121.711 us; speedup vs baseline: 1.7015x; 1.0993x over previous
//
#include <hip/hip_runtime.h>
#include <math.h>

#define BB 4
#define CC 64
#define TT 128
#define QQ 128
#define KK 8
#define HH 128
#define NN 512
#define LL 121
#define LPAD 135

typedef unsigned short ushort;
typedef __attribute__((ext_vector_type(8))) short short8;
typedef __attribute__((ext_vector_type(4))) float f32x4;
typedef __attribute__((ext_vector_type(4))) float float4v;

#define GLP(p) ((const __attribute__((address_space(1))) void*)(p))
#define LDP(p) ((__attribute__((address_space(3))) void*)(p))

__device__ __forceinline__ ushort f2bf(float x) {
  unsigned u = __float_as_uint(x);
  unsigned r = (u + 0x7FFFu + ((u >> 16) & 1u)) >> 16;
  return (ushort)r;
}

// ---- merged prep: LayerNorm->xT, weight transforms, zero page ----
__global__ __launch_bounds__(256)
void prep_all(const float* __restrict__ f, const float* __restrict__ gamma,
              const float* __restrict__ beta, const float* __restrict__ wf,
              const float* __restrict__ wb, const float* __restrict__ ctw,
              ushort* __restrict__ xT, ushort* __restrict__ Wt,
              ushort* __restrict__ Bct, ushort* __restrict__ zpage) {
  int bid = blockIdx.x, tid = threadIdx.x;
  if (bid < 256) {                       // --- LayerNorm -> xT[n][q][c] bf16
    int p = bid * 256 + tid;
    int q = p & (QQ - 1);
    int t = (p >> 7) & (TT - 1);
    int b = p >> 14;
    const float* base = f + (size_t)b * CC * TT * QQ + (size_t)t * QQ + q;
    float v[64];
#pragma unroll
    for (int c = 0; c < 64; ++c) v[c] = base[(size_t)c * TT * QQ];
    float s = 0.f, s2 = 0.f;
#pragma unroll
    for (int c = 0; c < 64; ++c) { s += v[c]; s2 += v[c] * v[c]; }
    float mu = s * (1.f / CC);
    float var = s2 * (1.f / CC) - mu * mu;
    float rs = rsqrtf(var + 1e-5f);
    int n = b * TT + t;
    ushort* dst = xT + (size_t)n * (CC * QQ) + (size_t)q * CC;
#pragma unroll
    for (int v8 = 0; v8 < 8; ++v8) {
      short8 ov;
#pragma unroll
      for (int e = 0; e < 8; ++e) {
        int c = v8 * 8 + e;
        ov[e] = (short)f2bf((v[c] - mu) * rs * gamma[c] + beta[c]);
      }
      *(short8*)(dst + v8 * 8) = ov;
    }
  } else if (bid < 2816) {               // --- Wt / Bct transforms
    int idx = (bid - 256) * 256 + tid;
    if (idx < 524288) {
      // Wt[r][d], d=k*64+c; col r: dir=r>>9,t=r&511,
      // h=(t>>7)*32+((t>>6)&1)*16+(t&15), quad=(t>>4)&3
      int r = idx >> 9, d = idx & 511;
      int k = d >> 6, c = d & 63;
      int dir = r >> 9, t = r & 511;
      int h = (t >> 7) * 32 + ((t >> 6) & 1) * 16 + (t & 15);
      int quad = (t >> 4) & 3;
      const float* w = dir ? wb : wf;
      Wt[idx] = f2bf(w[(size_t)(c * 8 + k) * 512 + quad * 128 + h]);
    } else {
      int i2 = idx - 524288;             // 64*2048
      int c = i2 >> 11, d = i2 & 2047;
      int k = d >> 8, j = d & 255;
      Bct[i2] = f2bf(ctw[(size_t)j * (CC * KK) + c * KK + k]);
    }
  } else {                               // --- zero page (512 B)
    if (tid < 128) ((unsigned*)zpage)[tid] = 0u;
  }
}

// ---- fused MFMA GEMM, BM=128 x BN=256, 4 waves 1Mx4N (R11 geometry) ----
// NEW: A is a SLIDING WINDOW over xT rows (step ks uses rows ks..ks+127), so
// the window (135 rows, 17 KB) is staged ONCE into Hs; the K-loop stages only
// B (8 loads/thread/step, was 12). XOR key ((row>>3)^row)&7 swizzles both the
// staging source and the MFMA read slot. Output rows per thread remain
// CONTIGUOUS l = lk*32 + m*4 + g (A MFMA-row r reads Hs row f(r)+ks).
// Epilogue: wave-local in-register scan + 8 shuffles. Zero barriers, zero LDS.
__global__ __launch_bounds__(256, 2)
void gemm_mfma(const ushort* __restrict__ xT, const ushort* __restrict__ Wt,
               const float* __restrict__ b_fwd, const float* __restrict__ b_bwd,
               ushort* __restrict__ hp, int n0) {
  __shared__ __align__(16) char smem[51200];
  ushort* Hs = (ushort*)smem;                 // 18.4 KB: 144 rows x 64 (A window)
  ushort* Bs = (ushort*)(smem + 18432);       // 32 KB (256x64)

  int tid = threadIdx.x;
  int nl = blockIdx.y;
  int r0 = blockIdx.x * 256;
  int lane = tid & 63, w = tid >> 6;
  int lrow = lane & 15, lk = lane >> 4;
  f32x4 acc[8][4] = {};
  const ushort* xTn = xT + (size_t)(n0 + nl) * (CC * QQ);

  // ---- stage A window ONCE: xT rows 0..134 (rows 135..143 clamped slop) ----
#pragma unroll
  for (int i = 0; i < 4; ++i) {
    int p = i * 256 + tid;
    int row = p >> 3, s3 = p & 7;
    int key = ((row >> 3) ^ row) & 7;
    const ushort* g = xTn + (size_t)row * CC + (s3 ^ key) * 8;
    ushort* l = &Hs[(size_t)(i * 256 + (tid & 192)) * 8];
    __builtin_amdgcn_global_load_lds(GLP(g), LDP(l), 16, 0, 0);
  }
  if (tid < 128) {                            // wave-uniform (waves 0,1 only)
    int p = 1024 + tid;
    int row = p >> 3, s3 = p & 7;
    int srow = row < 135 ? row : 134;         // keep reads in-bounds
    int key = ((row >> 3) ^ row) & 7;
    const ushort* g = xTn + (size_t)srow * CC + (s3 ^ key) * 8;
    ushort* l = &Hs[(size_t)(1024 + (tid & 64)) * 8];
    __builtin_amdgcn_global_load_lds(GLP(g), LDP(l), 16, 0, 0);
  }

#define GEMM_BSTAGE(KS)                                                   \
  {                                                                       \
    _Pragma("unroll")                                                     \
    for (int i = 0; i < 8; ++i) {                                         \
      int p = i * 256 + tid;                                              \
      int row = p >> 3, s3 = (p & 7) ^ (row & 7);                         \
      const ushort* g = Wt + (size_t)(r0 + row) * 512 + (KS) * 64 + s3 * 8; \
      ushort* l = &Bs[(size_t)(i * 256 + (tid & 192)) * 8];               \
      __builtin_amdgcn_global_load_lds(GLP(g), LDP(l), 16, 0, 0);         \
    }                                                                     \
  }

  GEMM_BSTAGE(0);
  __syncthreads();
  int RLb = ((lrow & 0x0C) << 3) | (lrow & 3);
  for (int ks = 0; ks < 8; ++ks) {
#pragma unroll
    for (int s = 0; s < 2; ++s) {
      short8 a[8], b[4];
#pragma unroll
      for (int m = 0; m < 8; ++m) {
        int R = RLb + m * 4 + ks;             // Hs row for MFMA-row m*16+lrow
        int key = ((R >> 3) ^ R) & 7;
        int slot = (s * 4 + lk) ^ key;
        a[m] = *(const short8*)&Hs[R * 64 + slot * 8];
      }
#pragma unroll
      for (int nn = 0; nn < 4; ++nn) {
        int j = w * 64 + nn * 16 + lrow;
        int slot = (s * 4 + lk) ^ (j & 7);
        b[nn] = *(const short8*)&Bs[j * 64 + slot * 8];
      }
#pragma unroll
      for (int m = 0; m < 8; ++m)
#pragma unroll
        for (int nn = 0; nn < 4; ++nn)
          acc[m][nn] = __builtin_amdgcn_mfma_f32_16x16x32_bf16(
              a[m], b[nn], acc[m][nn], 0, 0, 0);
    }
    if (ks < 7) {
      __syncthreads();
      GEMM_BSTAGE(ks + 1);
      __syncthreads();
    }
  }
#undef GEMM_BSTAGE

  // ---- epilogue: wave-local scan, no barriers ----
  int dirf = r0 >> 9;
  int hgroup = ((r0 & 511) >> 7) + (w >> 1);
  int h = hgroup * 32 + (w & 1) * 16 + lrow;
  const float* bias = dirf ? b_bwd : b_fwd;
  float bf = bias[h], br = bias[128 + h];

  // serial scan of this thread's 32 contiguous l, in-place into acc[m][0/1]
  float F = 1.f, U = 0.f;
  if (dirf == 0) {
#pragma unroll
    for (int m = 0; m < 8; ++m)
#pragma unroll
      for (int g = 0; g < 4; ++g) {
        int l = lk * 32 + m * 4 + g;
        float xt = acc[m][0][g], fp = acc[m][1][g];
        float fg = 1.f / (1.f + __expf(-(fp + bf)));
        float u = (1.f - fg) * xt;
        if (l > 120) { fg = 1.f; u = 0.f; }   // identity (kills garbage rows)
        U = fg * U + u;
        F = fg * F;
        acc[m][0][g] = F; acc[m][1][g] = U;
      }
  } else {
#pragma unroll
    for (int m = 7; m >= 0; --m)
#pragma unroll
      for (int g = 3; g >= 0; --g) {
        int l = lk * 32 + m * 4 + g;
        float xt = acc[m][0][g], fp = acc[m][1][g];
        float fg = 1.f / (1.f + __expf(-(fp + bf)));
        float u = (1.f - fg) * xt;
        if (l > 120) { fg = 1.f; u = 0.f; }
        U = fg * U + u;
        F = fg * F;
        acc[m][0][g] = F; acc[m][1][g] = U;
      }
  }
  // compose across lk chunks (full 128-l chain in this wave): 8 shuffles
  int e = dirf ? 3 - lk : lk;
  float lpU = 0.f;
#pragma unroll
  for (int j = 0; j < 4; ++j) {
    int jl = dirf ? 3 - j : j;
    float tF = __shfl(F, (jl << 4) + lrow);
    float tU = __shfl(U, (jl << 4) + lrow);
    if (j < e) lpU = tF * lpU + tU;
  }
  float cinit = lpU;
  // apply: c = U + F*cinit; h_out = r*tanh(c) + (1-r)*xp -> bf16 hp
  // UNCONDITIONAL stores: garbage l>120 land in hp rows 128..134 (never read;
  // conv redirects pad reads to the zero page).
  ushort* hpn = hp + (size_t)nl * LPAD * 256;
  int colbase = dirf * 128 + hgroup * 32 + (w & 1) * 16;
#pragma unroll
  for (int m = 0; m < 8; ++m) {
#pragma unroll
    for (int g = 0; g < 4; ++g) {
      int l = lk * 32 + m * 4 + g;
      float c = acc[m][1][g] + acc[m][0][g] * cinit;
      float rp = acc[m][2][g];
      float rg = 1.f / (1.f + __expf(-(rp + br)));
      float e2 = __expf(2.f * c);
      float th = (e2 - 1.f) / (e2 + 1.f);
      float ho = rg * th + (1.f - rg) * acc[m][3][g];
      hpn[(size_t)(l + 7) * 256 + colbase + lrow] = f2bf(ho);
    }
  }
}

// ---------------- ConvTranspose as MFMA GEMM, persistent-Hs version ----------------
__global__ __launch_bounds__(256)
void conv_mfma(const ushort* __restrict__ hp, const ushort* __restrict__ Bct,
               const ushort* __restrict__ zpage, const float* __restrict__ ctb,
               const float* __restrict__ feat, float* __restrict__ out, int n0) {
  __shared__ __align__(16) ushort Hs[144 * 128];   // 36,864 B (rows 135..143 = slop)
  __shared__ __align__(16) ushort Bs[2][64 * 64];  // 16,384 B
  int tid = threadIdx.x;
  int nl = blockIdx.x;
  int lane = tid & 63, w = tid >> 6;
  int wr0 = (w >> 1) * 64, wc0 = (w & 1) * 32;
  int lrow = lane & 15, lk = lane >> 4;
  f32x4 acc[4][2] = {};
  const ushort* hpn = hp + (size_t)nl * LPAD * 256;

#define CONV_BSTAGE(T, BSEL)                                               \
  {                                                                        \
    int kk_ = (T) >> 1, sub_ = (T) & 1;                                    \
    _Pragma("unroll")                                                      \
    for (int i = 0; i < 2; ++i) {                                          \
      int p = i * 256 + tid;                                               \
      int row = p >> 3, ds = p & 7;                                        \
      const ushort* g = Bct + (size_t)row * 2048 + kk_ * 256 + jh * 128    \
                      + sub_ * 64 + (ds ^ (row & 7)) * 8;                  \
      ushort* l = &Bs[BSEL][(size_t)(i * 256 + (tid & 192)) * 8];          \
      __builtin_amdgcn_global_load_lds(GLP(g), LDP(l), 16, 0, 0);          \
    }                                                                      \
  }

  for (int jh = 0; jh < 2; ++jh) {
    // stage Hs: hp rows 0..143 of this j-half; rows outside [7,127] -> zeros
#pragma unroll
    for (int r = 0; r < 9; ++r) {
      int p = r * 256 + tid;
      int row = p >> 4, ds = p & 15;
      int cs = (ds & 8) | ((ds & 7) ^ (row & 7));
      const ushort* g = ((unsigned)(row - 7) <= 120u)
          ? hpn + (size_t)row * 256 + jh * 128 + cs * 8
          : zpage;
      ushort* l = &Hs[(size_t)(r * 256 + (tid & 192)) * 8];
      __builtin_amdgcn_global_load_lds(GLP(g), LDP(l), 16, 0, 0);
    }
    CONV_BSTAGE(0, 0);
    __syncthreads();
    for (int t = 0; t < 16; ++t) {
      int cur = t & 1;
      if (t < 15) CONV_BSTAGE(t + 1, cur ^ 1);
      int kk = t >> 1, sub = t & 1;
#pragma unroll
      for (int s = 0; s < 2; ++s) {
        short8 a[4], b[2];
#pragma unroll
        for (int m = 0; m < 4; ++m) {
          int row = wr0 + m * 16 + lrow + 7 - kk;
          int slot = (sub * 8) | ((s * 4 + lk) ^ (row & 7));
          a[m] = *(const short8*)&Hs[row * 128 + slot * 8];
        }
#pragma unroll
        for (int nn = 0; nn < 2; ++nn) {
          int c = wc0 + nn * 16 + lrow;
          int slot = (s * 4 + lk) ^ (c & 7);
          b[nn] = *(const short8*)&Bs[cur][c * 64 + slot * 8];
        }
#pragma unroll
        for (int m = 0; m < 4; ++m)
#pragma unroll
          for (int nn = 0; nn < 2; ++nn)
            acc[m][nn] = __builtin_amdgcn_mfma_f32_16x16x32_bf16(
                a[m], b[nn], acc[m][nn], 0, 0, 0);
      }
      __syncthreads();
    }
  }
#undef CONV_BSTAGE
  int n = n0 + nl;
  int b = n >> 7, t = n & 127;
#pragma unroll
  for (int m = 0; m < 4; ++m) {
    int q0 = wr0 + m * 16 + lk * 4;
#pragma unroll
    for (int nn = 0; nn < 2; ++nn) {
      int c = wc0 + nn * 16 + lrow;
      size_t idx = (size_t)b * (CC * TT * QQ) + (size_t)c * (TT * QQ)
                 + (size_t)t * QQ + q0;
      float4v fv = *(const float4v*)&feat[idx];
      float cb = ctb[c];
      float4v ov;
#pragma unroll
      for (int g = 0; g < 4; ++g) ov[g] = acc[m][nn][g] + cb + fv[g];
      *(float4v*)&out[idx] = ov;
    }
  }
}

extern "C" void kernel_launch(void* const* d_in, const int* in_sizes, int n_in,
                              void* d_out, int out_size, void* d_ws, size_t ws_size,
                              hipStream_t stream) {
  const float* feat  = (const float*)d_in[0];
  const float* gamma = (const float*)d_in[1];
  const float* beta  = (const float*)d_in[2];
  const float* w_fwd = (const float*)d_in[3];
  const float* b_fwd = (const float*)d_in[4];
  const float* w_bwd = (const float*)d_in[5];
  const float* b_bwd = (const float*)d_in[6];
  const float* ct_w  = (const float*)d_in[7];
  const float* ct_b  = (const float*)d_in[8];
  float* out = (float*)d_out;

  char* wsb = (char*)d_ws;
  ushort* xT  = (ushort*)wsb;                         // 8,388,608 B (+1 KB pad)
  ushort* Wt  = (ushort*)(wsb + 8389632);             // 1,048,576 B
  ushort* Bct = (ushort*)(wsb + 9438208);             //   262,144 B
  ushort* zpg = (ushort*)(wsb + 9700352);             //       512 B
  size_t persist = 9700864;
  size_t per_n = 69120u;                              // hp only
  int NC = 4;
  for (int cand = 512; cand >= 4; cand >>= 1) {
    if (persist + (size_t)cand * per_n <= ws_size) { NC = cand; break; }
  }
  ushort* hpc = (ushort*)(wsb + persist);

  prep_all<<<dim3(2817), dim3(256), 0, stream>>>(feat, gamma, beta, w_fwd,
                                                 w_bwd, ct_w, xT, Wt, Bct, zpg);

  for (int n0 = 0; n0 < NN; n0 += NC) {
    gemm_mfma<<<dim3(4, NC), dim3(256), 0, stream>>>(xT, Wt, b_fwd, b_bwd,
                                                     hpc, n0);
    conv_mfma<<<dim3(NC), dim3(256), 0, stream>>>(hpc, Bct, zpg, ct_b, feat,
                                                  out, n0);
  }
}